// Round 1
// baseline (1082.504 us; speedup 1.0000x reference)
//
#include <hip/hip_runtime.h>
#include <hip/hip_bf16.h>

// Problem constants
#define BT 32768      // B*T = 64*512
#define TSTEPS 512
#define NBATCH 64
#define KDIM 512      // IN_DIM
#define NP 204        // 132 (lstm z) + 4*18 (layer0 precomp)
#define NPAD 208      // P row stride (float4-friendly)
#define NW 256        // Wc padded cols

__device__ __forceinline__ float fsig(float x) { return 1.f / (1.f + __expf(-x)); }
__device__ __forceinline__ float ftanh(float x) {
    float xc = fminf(fmaxf(x, -15.f), 15.f);
    float e = __expf(2.f * xc);
    return (e - 1.f) / (e + 1.f);
}

// ---------------------------------------------------------------------------
// Kernel 1: fold fc1 into the stacked scan-input projection.
// Wbig rows (204): [0,132) lstm_wi; [132,150) ff1w0*mask0 (u part);
// [150,168) ff2w0*mask0; [168,186) taw0; [186,204) tbw0.
// Wc[d][o] = sum_l fc1_w[l][d] * Wbig[o][l]   (Wc is [512][256], cols>=204 zero)
// bc[o]    = sum_l fc1_b[l]    * Wbig[o][l] + bias0[o]
// ---------------------------------------------------------------------------
__global__ __launch_bounds__(256) void fold_kernel(
    const float* __restrict__ fc1_w, const float* __restrict__ fc1_b,
    const float* __restrict__ lstm_wi, const float* __restrict__ lstm_bi,
    const float* __restrict__ ff1w0, const float* __restrict__ ff2w0,
    const float* __restrict__ taw0, const float* __restrict__ tbw0,
    const float* __restrict__ ff1b0, const float* __restrict__ ff2b0,
    const float* __restrict__ tab0, const float* __restrict__ tbb0,
    const float* __restrict__ mask0,
    float* __restrict__ Wc, float* __restrict__ bc)
{
    const int o = blockIdx.x;   // 0..255
    const int t = threadIdx.x;  // 0..255 = latent index l
    __shared__ float wrow[256];
    __shared__ float red[256];

    float wl = 0.f, b0 = 0.f;
    if (o < 132)      { wl = lstm_wi[o * 256 + t];                         b0 = lstm_bi[o]; }
    else if (o < 150) { int i = o - 132; wl = ff1w0[i * 274 + t] * mask0[i * 274 + t]; b0 = ff1b0[i]; }
    else if (o < 168) { int i = o - 150; wl = ff2w0[i * 274 + t] * mask0[i * 274 + t]; b0 = ff2b0[i]; }
    else if (o < 186) { int i = o - 168; wl = taw0[i * 274 + t];           b0 = tab0[i]; }
    else if (o < 204) { int i = o - 186; wl = tbw0[i * 274 + t];           b0 = tbb0[i]; }
    wrow[t] = wl;
    __syncthreads();

    float acc0 = 0.f, acc1 = 0.f;
    for (int l = 0; l < 256; l++) {
        float w = wrow[l];
        acc0 = fmaf(fc1_w[l * 512 + t], w, acc0);
        acc1 = fmaf(fc1_w[l * 512 + t + 256], w, acc1);
    }
    Wc[(size_t)t * NW + o] = acc0;
    Wc[(size_t)(t + 256) * NW + o] = acc1;

    red[t] = fc1_b[t] * wl;
    __syncthreads();
    for (int s = 128; s > 0; s >>= 1) {
        if (t < s) red[t] += red[t + s];
        __syncthreads();
    }
    if (t == 0) bc[o] = red[0] + b0;
}

// ---------------------------------------------------------------------------
// Kernel 2: P[m][n] = sum_k X[m][k]*Wc[k][n] + bc[n], fp32 LDS-tiled GEMM.
// M=32768, K=512, N=256 (padded; stores guarded to n<208). Tile 64x64x16.
// ---------------------------------------------------------------------------
__global__ __launch_bounds__(256) void gemm_kernel(
    const float* __restrict__ X, const float* __restrict__ Wc,
    const float* __restrict__ bc, float* __restrict__ P)
{
    __shared__ float As[16][68];   // [k][m], padded for alignment/banks
    __shared__ float Bs[16][64];   // [k][n]
    const int tid = threadIdx.x;
    const int m0 = blockIdx.x * 64;
    const int n0 = blockIdx.y * 64;
    const int lr = tid >> 2;            // A loader: row 0..63
    const int lc = (tid & 3) << 2;      // A loader: k-col 0,4,8,12
    const int wr = tid >> 4;            // B loader: k-row 0..15
    const int wc = (tid & 15) << 2;     // B loader: n-col
    const int tm = (tid >> 4) << 2;     // compute: 4 rows
    const int tn = (tid & 15) << 2;     // compute: 4 cols

    float acc[4][4];
#pragma unroll
    for (int i = 0; i < 4; i++)
#pragma unroll
        for (int j = 0; j < 4; j++) acc[i][j] = 0.f;

    for (int k0 = 0; k0 < KDIM; k0 += 16) {
        float4 av = *(const float4*)(X + (size_t)(m0 + lr) * KDIM + k0 + lc);
        float4 bv = *(const float4*)(Wc + (size_t)(k0 + wr) * NW + n0 + wc);
        __syncthreads();
        As[lc + 0][lr] = av.x; As[lc + 1][lr] = av.y;
        As[lc + 2][lr] = av.z; As[lc + 3][lr] = av.w;
        *(float4*)&Bs[wr][wc] = bv;
        __syncthreads();
#pragma unroll
        for (int k = 0; k < 16; k++) {
            float4 a = *(const float4*)&As[k][tm];
            float4 b = *(const float4*)&Bs[k][tn];
            acc[0][0] = fmaf(a.x, b.x, acc[0][0]); acc[0][1] = fmaf(a.x, b.y, acc[0][1]);
            acc[0][2] = fmaf(a.x, b.z, acc[0][2]); acc[0][3] = fmaf(a.x, b.w, acc[0][3]);
            acc[1][0] = fmaf(a.y, b.x, acc[1][0]); acc[1][1] = fmaf(a.y, b.y, acc[1][1]);
            acc[1][2] = fmaf(a.y, b.z, acc[1][2]); acc[1][3] = fmaf(a.y, b.w, acc[1][3]);
            acc[2][0] = fmaf(a.z, b.x, acc[2][0]); acc[2][1] = fmaf(a.z, b.y, acc[2][1]);
            acc[2][2] = fmaf(a.z, b.z, acc[2][2]); acc[2][3] = fmaf(a.z, b.w, acc[2][3]);
            acc[3][0] = fmaf(a.w, b.x, acc[3][0]); acc[3][1] = fmaf(a.w, b.y, acc[3][1]);
            acc[3][2] = fmaf(a.w, b.z, acc[3][2]); acc[3][3] = fmaf(a.w, b.w, acc[3][3]);
        }
    }

    if (n0 + tn < NPAD) {
        float4 bias = *(const float4*)(bc + n0 + tn);
#pragma unroll
        for (int i = 0; i < 4; i++) {
            float4 r;
            r.x = acc[i][0] + bias.x; r.y = acc[i][1] + bias.y;
            r.z = acc[i][2] + bias.z; r.w = acc[i][3] + bias.w;
            *(float4*)(P + (size_t)(m0 + tm + i) * NPAD + n0 + tn) = r;
        }
    }
}

// ---------------------------------------------------------------------------
// Kernel 3: persistent scan. One wave (64 threads) per batch element, loops
// over T=512 steps. Recurrent weights live in VGPRs; state/broadcast via LDS.
// P row layout (204): [0,132) z precomp (incl lstm_bi); [132,204) layer0
// precomp stacked as d = m*18+i, m in {ff1,ff2,ta,tb} (incl biases).
// ---------------------------------------------------------------------------
__global__ __launch_bounds__(64) void scan_kernel(
    const float* __restrict__ P, const float* __restrict__ lstm_wh,
    const float* __restrict__ ff1w0, const float* __restrict__ ff2w0,
    const float* __restrict__ taw0, const float* __restrict__ tbw0,
    const float* __restrict__ ff1w1, const float* __restrict__ ff2w1,
    const float* __restrict__ taw1, const float* __restrict__ tbw1,
    const float* __restrict__ ff1b1, const float* __restrict__ ff2b1,
    const float* __restrict__ tab1, const float* __restrict__ tbb1,
    const float* __restrict__ ff1w2, const float* __restrict__ ff2w2,
    const float* __restrict__ taw2, const float* __restrict__ tbw2,
    const float* __restrict__ ff1b2, const float* __restrict__ ff2b2,
    const float* __restrict__ tab2, const float* __restrict__ tbb2,
    const float* __restrict__ mask1, const float* __restrict__ mask2,
    float* __restrict__ out)
{
    const int L = threadIdx.x;
    const int b = blockIdx.x;

    __shared__ __align__(16) float hcar[36];  // carry h (CfC output state), 33
    __shared__ __align__(16) float hl[36];    // LSTM-gated h, 33
    __shared__ float zl[132];
    __shared__ float pl0[72];
    __shared__ float s0[72];
    __shared__ __align__(16) float xc1[32];   // 30 used
    __shared__ float s1[48];
    __shared__ __align__(16) float xc2[16];   // 15 used
    __shared__ float s2[12];

    // ---- stage recurrent weights into registers (constant over t) ----
    float whr0[33], whr1[33], whr2[33];
#pragma unroll
    for (int j = 0; j < 33; j++) {
        whr0[j] = lstm_wh[L * 33 + j];
        whr1[j] = lstm_wh[(64 + L) * 33 + j];
        whr2[j] = (L < 4) ? lstm_wh[(128 + L) * 33 + j] : 0.f;
    }
    // layer0 h-part (cols 256..273; mask ones there, ta/tb unmasked anyway)
    const int m0i = L / 18, i0 = L - m0i * 18;   // d0 = L in [0,64)
    const float* w0s = (m0i == 0) ? ff1w0 : (m0i == 1) ? ff2w0 : (m0i == 2) ? taw0 : tbw0;
    float w0r0[18], w0r1[18];
#pragma unroll
    for (int j = 0; j < 18; j++) {
        w0r0[j] = w0s[i0 * 274 + 256 + j];
        w0r1[j] = (L < 8) ? tbw0[(10 + L) * 274 + 256 + j] : 0.f;  // d1=64+L -> tb rows 10..17
    }
    // layer1 full rows (48 dots of len 30), ff1/ff2 masked
    float w1r[30]; float b1r = 0.f;
    {
        int m = L / 12, i = L - m * 12;
        if (L < 48) {
            const float* ws = (m == 0) ? ff1w1 : (m == 1) ? ff2w1 : (m == 2) ? taw1 : tbw1;
            const float* bs = (m == 0) ? ff1b1 : (m == 1) ? ff2b1 : (m == 2) ? tab1 : tbb1;
            b1r = bs[i];
#pragma unroll
            for (int j = 0; j < 30; j++) {
                float mm = (m < 2) ? mask1[i * 30 + j] : 1.f;
                w1r[j] = ws[i * 30 + j] * mm;
            }
        } else {
#pragma unroll
            for (int j = 0; j < 30; j++) w1r[j] = 0.f;
        }
    }
    // layer2 full rows (12 dots of len 15)
    float w2r[15]; float b2r = 0.f;
    {
        int m = L / 3, i = L - m * 3;
        if (L < 12) {
            const float* ws = (m == 0) ? ff1w2 : (m == 1) ? ff2w2 : (m == 2) ? taw2 : tbw2;
            const float* bs = (m == 0) ? ff1b2 : (m == 1) ? ff2b2 : (m == 2) ? tab2 : tbb2;
            b2r = bs[i];
#pragma unroll
            for (int j = 0; j < 15; j++) {
                float mm = (m < 2) ? mask2[i * 15 + j] : 1.f;
                w2r[j] = ws[i * 15 + j] * mm;
            }
        } else {
#pragma unroll
            for (int j = 0; j < 15; j++) w2r[j] = 0.f;
        }
    }

    if (L < 36) hcar[L] = 0.f;
    float c = 0.f;

    const float* Pb = P + (size_t)b * TSTEPS * NPAD;
    float pa = Pb[L], pb_ = Pb[64 + L], pc = Pb[128 + L];
    float pd = (L < 12) ? Pb[192 + L] : 0.f;
    __syncthreads();

    for (int t = 0; t < TSTEPS; t++) {
        // stage layer0 precomp into LDS (pc holds P[132+L-4] for L>=4)
        if (L >= 4) pl0[L - 4] = pc;
        if (L < 12) pl0[60 + L] = pd;

        // prefetch next step's P row (latency hidden under this step)
        const float* Pn = Pb + (size_t)((t < TSTEPS - 1) ? t + 1 : t) * NPAD;
        float na = Pn[L], nb = Pn[64 + L], nc = Pn[128 + L];
        float nd = (L < 12) ? Pn[192 + L] : 0.f;

        // ---- z = P_z + hcar @ lstm_wh^T  (132 outputs, 2-3 per lane) ----
        float hreg[33];
#pragma unroll
        for (int j4 = 0; j4 < 32; j4 += 4) {
            float4 h4 = *(const float4*)&hcar[j4];
            hreg[j4] = h4.x; hreg[j4 + 1] = h4.y; hreg[j4 + 2] = h4.z; hreg[j4 + 3] = h4.w;
        }
        hreg[32] = hcar[32];
        float a0 = pa, a1 = pb_, a2 = pc;
#pragma unroll
        for (int j = 0; j < 33; j++) {
            a0 = fmaf(whr0[j], hreg[j], a0);
            a1 = fmaf(whr1[j], hreg[j], a1);
            a2 = fmaf(whr2[j], hreg[j], a2);
        }
        zl[L] = a0; zl[64 + L] = a1;
        if (L < 4) zl[128 + L] = a2;
        __syncthreads();  // S2

        // ---- LSTM gates (lanes 0..32) ----
        if (L < 33) {
            float ia = zl[L], ig = zl[33 + L], fg = zl[66 + L], og = zl[99 + L];
            c = c * fsig(fg + 1.f) + ftanh(ia) * fsig(ig);
            hl[L] = ftanh(c) * fsig(og);
        }
        __syncthreads();  // S3

        // ---- layer0 dots: 72 dots of len 18 over hl[0..17] ----
        {
            float h0r[18];
#pragma unroll
            for (int j4 = 0; j4 < 16; j4 += 4) {
                float4 h4 = *(const float4*)&hl[j4];
                h0r[j4] = h4.x; h0r[j4 + 1] = h4.y; h0r[j4 + 2] = h4.z; h0r[j4 + 3] = h4.w;
            }
            h0r[16] = hl[16]; h0r[17] = hl[17];
            float d0a = pl0[L];
            float d1a = (L < 8) ? pl0[64 + L] : 0.f;
#pragma unroll
            for (int j = 0; j < 18; j++) {
                d0a = fmaf(w0r0[j], h0r[j], d0a);
                d1a = fmaf(w0r1[j], h0r[j], d1a);
            }
            s0[L] = d0a;
            if (L < 8) s0[64 + L] = d1a;
            if (L >= 18 && L < 30) xc1[L] = hl[L];  // command-part of xc1
        }
        __syncthreads();  // S4

        // ---- layer0 combine (lanes 0..17) ----
        if (L < 18) {
            float f1 = ftanh(s0[L]), f2 = ftanh(s0[18 + L]);
            float ti = fsig(s0[36 + L] + s0[54 + L]);
            float h0 = f1 + ti * (f2 - f1);
            xc1[L] = h0; hcar[L] = h0;
        }
        __syncthreads();  // S5

        // ---- layer1 dots: 48 dots of len 30 over xc1 ----
        {
            float x1r[30];
#pragma unroll
            for (int j4 = 0; j4 < 28; j4 += 4) {
                float4 x4 = *(const float4*)&xc1[j4];
                x1r[j4] = x4.x; x1r[j4 + 1] = x4.y; x1r[j4 + 2] = x4.z; x1r[j4 + 3] = x4.w;
            }
            x1r[28] = xc1[28]; x1r[29] = xc1[29];
            float a = b1r;
#pragma unroll
            for (int j = 0; j < 30; j++) a = fmaf(w1r[j], x1r[j], a);
            if (L < 48) s1[L] = a;
            if (L >= 12 && L < 15) xc2[L] = hl[18 + L];  // motor-part: hl[30..32]
        }
        __syncthreads();  // S6

        // ---- layer1 combine (lanes 0..11) ----
        if (L < 12) {
            float f1 = ftanh(s1[L]), f2 = ftanh(s1[12 + L]);
            float ti = fsig(s1[24 + L] + s1[36 + L]);
            float h1 = f1 + ti * (f2 - f1);
            xc2[L] = h1; hcar[18 + L] = h1;
        }
        __syncthreads();  // S7

        // ---- layer2 dots: 12 dots of len 15 over xc2 ----
        {
            float x2r[15];
#pragma unroll
            for (int j4 = 0; j4 < 12; j4 += 4) {
                float4 x4 = *(const float4*)&xc2[j4];
                x2r[j4] = x4.x; x2r[j4 + 1] = x4.y; x2r[j4 + 2] = x4.z; x2r[j4 + 3] = x4.w;
            }
            x2r[12] = xc2[12]; x2r[13] = xc2[13]; x2r[14] = xc2[14];
            float a = b2r;
#pragma unroll
            for (int j = 0; j < 15; j++) a = fmaf(w2r[j], x2r[j], a);
            if (L < 12) s2[L] = a;
        }
        __syncthreads();  // S8

        // ---- layer2 combine (lanes 0..2): motor output ----
        if (L < 3) {
            float f1 = ftanh(s2[L]), f2 = ftanh(s2[3 + L]);
            float ti = fsig(s2[6 + L] + s2[9 + L]);
            float h2 = f1 + ti * (f2 - f1);
            out[((size_t)b * TSTEPS + t) * 3 + L] = h2;
            hcar[30 + L] = h2;
        }
        __syncthreads();  // S1 of next iteration

        pa = na; pb_ = nb; pc = nc; pd = nd;
    }
}

// ---------------------------------------------------------------------------
extern "C" void kernel_launch(void* const* d_in, const int* in_sizes, int n_in,
                              void* d_out, int out_size, void* d_ws, size_t ws_size,
                              hipStream_t stream) {
    const float* x       = (const float*)d_in[0];
    const float* fc1_w   = (const float*)d_in[1];
    const float* fc1_b   = (const float*)d_in[2];
    const float* lstm_wi = (const float*)d_in[3];
    const float* lstm_bi = (const float*)d_in[4];
    const float* lstm_wh = (const float*)d_in[5];
    const float* ff1w0 = (const float*)d_in[6];
    const float* ff2w0 = (const float*)d_in[7];
    const float* taw0  = (const float*)d_in[8];
    const float* tbw0  = (const float*)d_in[9];
    const float* ff1b0 = (const float*)d_in[10];
    const float* ff2b0 = (const float*)d_in[11];
    const float* tab0  = (const float*)d_in[12];
    const float* tbb0  = (const float*)d_in[13];
    const float* ff1w1 = (const float*)d_in[14];
    const float* ff2w1 = (const float*)d_in[15];
    const float* taw1  = (const float*)d_in[16];
    const float* tbw1  = (const float*)d_in[17];
    const float* ff1b1 = (const float*)d_in[18];
    const float* ff2b1 = (const float*)d_in[19];
    const float* tab1  = (const float*)d_in[20];
    const float* tbb1  = (const float*)d_in[21];
    const float* ff1w2 = (const float*)d_in[22];
    const float* ff2w2 = (const float*)d_in[23];
    const float* taw2  = (const float*)d_in[24];
    const float* tbw2  = (const float*)d_in[25];
    const float* ff1b2 = (const float*)d_in[26];
    const float* ff2b2 = (const float*)d_in[27];
    const float* tab2  = (const float*)d_in[28];
    const float* tbb2  = (const float*)d_in[29];
    // mask0 = d_in[30] used in fold; mask1/2 in scan
    const float* mask0 = (const float*)d_in[30];
    const float* mask1 = (const float*)d_in[31];
    const float* mask2 = (const float*)d_in[32];

    float* Wc = (float*)d_ws;            // 512*256 floats
    float* bc = Wc + 512 * NW;           // 256 floats
    float* P  = bc + NW;                 // 32768*208 floats (~27.3 MB total ws)
    float* outp = (float*)d_out;

    fold_kernel<<<256, 256, 0, stream>>>(fc1_w, fc1_b, lstm_wi, lstm_bi,
                                         ff1w0, ff2w0, taw0, tbw0,
                                         ff1b0, ff2b0, tab0, tbb0, mask0, Wc, bc);
    gemm_kernel<<<dim3(BT / 64, 4), 256, 0, stream>>>(x, Wc, bc, P);
    scan_kernel<<<NBATCH, 64, 0, stream>>>(P, lstm_wh,
                                           ff1w0, ff2w0, taw0, tbw0,
                                           ff1w1, ff2w1, taw1, tbw1,
                                           ff1b1, ff2b1, tab1, tbb1,
                                           ff1w2, ff2w2, taw2, tbw2,
                                           ff1b2, ff2b2, tab2, tbb2,
                                           mask1, mask2, outp);
}

// Round 2
// 919.271 us; speedup vs baseline: 1.1776x; 1.1776x over previous
//
#include <hip/hip_runtime.h>
#include <hip/hip_bf16.h>

// Problem constants
#define BT 32768      // B*T = 64*512
#define TSTEPS 512
#define NBATCH 64
#define KDIM 512      // IN_DIM
#define NPAD 208      // P row stride (permuted layout, float4-friendly)
#define NW 256        // Wc padded cols

__device__ __forceinline__ float fsig(float x) { return 1.f / (1.f + __expf(-x)); }
__device__ __forceinline__ float ftanh(float x) {
    float xc = fminf(fmaxf(x, -15.f), 15.f);
    float e = __expf(2.f * xc);
    return (e - 1.f) / (e + 1.f);
}
__device__ __forceinline__ float rl(float v, int lane) {
    return __int_as_float(__builtin_amdgcn_readlane(__float_as_int(v), lane));
}
__device__ __forceinline__ float cfc_comb(float a0, float a1, float a2, float a3) {
    float f1 = ftanh(a0), f2 = ftanh(a1);
    float ti = fsig(a2 + a3);
    return f1 + ti * (f2 - f1);
}

// Column permutation for P so the scan reads one float4 per lane per step:
//   z rows (o<132, o=g*33+i):        pos = 4*i+g          -> lane i reads [4i..4i+4) = (ia,ig,fg,og)
//   layer0 rows (o=132+m*18+i):      pos = 136+4*i+m      -> lane 34+i reads (ff1p,ff2p,tap,tbp)
//   pad/unused (204..207 -> 132..135), identity above 208.
__device__ __forceinline__ int permpos(int o) {
    if (o < 132) { int g = o / 33, i = o - g * 33; return 4 * i + g; }
    if (o < 204) { int j = o - 132; int m = j / 18, i = j - m * 18; return 136 + 4 * i + m; }
    if (o < 208) return 132 + (o - 204);
    return o;
}

// ---------------------------------------------------------------------------
// Kernel 1: fold fc1 into the stacked scan-input projection (permuted cols).
// ---------------------------------------------------------------------------
__global__ __launch_bounds__(256) void fold_kernel(
    const float* __restrict__ fc1_w, const float* __restrict__ fc1_b,
    const float* __restrict__ lstm_wi, const float* __restrict__ lstm_bi,
    const float* __restrict__ ff1w0, const float* __restrict__ ff2w0,
    const float* __restrict__ taw0, const float* __restrict__ tbw0,
    const float* __restrict__ ff1b0, const float* __restrict__ ff2b0,
    const float* __restrict__ tab0, const float* __restrict__ tbb0,
    const float* __restrict__ mask0,
    float* __restrict__ Wc, float* __restrict__ bc)
{
    const int o = blockIdx.x;   // 0..255 logical output column
    const int t = threadIdx.x;  // 0..255 = latent index l
    const int p = permpos(o);
    __shared__ float wrow[256];
    __shared__ float red[256];

    float wl = 0.f, b0 = 0.f;
    if (o < 132)      { wl = lstm_wi[o * 256 + t];                         b0 = lstm_bi[o]; }
    else if (o < 150) { int i = o - 132; wl = ff1w0[i * 274 + t] * mask0[i * 274 + t]; b0 = ff1b0[i]; }
    else if (o < 168) { int i = o - 150; wl = ff2w0[i * 274 + t] * mask0[i * 274 + t]; b0 = ff2b0[i]; }
    else if (o < 186) { int i = o - 168; wl = taw0[i * 274 + t];           b0 = tab0[i]; }
    else if (o < 204) { int i = o - 186; wl = tbw0[i * 274 + t];           b0 = tbb0[i]; }
    wrow[t] = wl;
    __syncthreads();

    float acc0 = 0.f, acc1 = 0.f;
    for (int l = 0; l < 256; l++) {
        float w = wrow[l];
        acc0 = fmaf(fc1_w[l * 512 + t], w, acc0);
        acc1 = fmaf(fc1_w[l * 512 + t + 256], w, acc1);
    }
    Wc[(size_t)t * NW + p] = acc0;
    Wc[(size_t)(t + 256) * NW + p] = acc1;

    red[t] = fc1_b[t] * wl;
    __syncthreads();
    for (int s = 128; s > 0; s >>= 1) {
        if (t < s) red[t] += red[t + s];
        __syncthreads();
    }
    if (t == 0) bc[p] = red[0] + b0;
}

// ---------------------------------------------------------------------------
// Kernel 2: P[m][n] = sum_k X[m][k]*Wc[k][n] + bc[n], fp32 LDS-tiled GEMM.
// ---------------------------------------------------------------------------
__global__ __launch_bounds__(256) void gemm_kernel(
    const float* __restrict__ X, const float* __restrict__ Wc,
    const float* __restrict__ bc, float* __restrict__ P)
{
    __shared__ float As[16][68];
    __shared__ float Bs[16][64];
    const int tid = threadIdx.x;
    const int m0 = blockIdx.x * 64;
    const int n0 = blockIdx.y * 64;
    const int lr = tid >> 2;
    const int lc = (tid & 3) << 2;
    const int wr = tid >> 4;
    const int wc = (tid & 15) << 2;
    const int tm = (tid >> 4) << 2;
    const int tn = (tid & 15) << 2;

    float acc[4][4];
#pragma unroll
    for (int i = 0; i < 4; i++)
#pragma unroll
        for (int j = 0; j < 4; j++) acc[i][j] = 0.f;

    for (int k0 = 0; k0 < KDIM; k0 += 16) {
        float4 av = *(const float4*)(X + (size_t)(m0 + lr) * KDIM + k0 + lc);
        float4 bv = *(const float4*)(Wc + (size_t)(k0 + wr) * NW + n0 + wc);
        __syncthreads();
        As[lc + 0][lr] = av.x; As[lc + 1][lr] = av.y;
        As[lc + 2][lr] = av.z; As[lc + 3][lr] = av.w;
        *(float4*)&Bs[wr][wc] = bv;
        __syncthreads();
#pragma unroll
        for (int k = 0; k < 16; k++) {
            float4 a = *(const float4*)&As[k][tm];
            float4 b = *(const float4*)&Bs[k][tn];
            acc[0][0] = fmaf(a.x, b.x, acc[0][0]); acc[0][1] = fmaf(a.x, b.y, acc[0][1]);
            acc[0][2] = fmaf(a.x, b.z, acc[0][2]); acc[0][3] = fmaf(a.x, b.w, acc[0][3]);
            acc[1][0] = fmaf(a.y, b.x, acc[1][0]); acc[1][1] = fmaf(a.y, b.y, acc[1][1]);
            acc[1][2] = fmaf(a.y, b.z, acc[1][2]); acc[1][3] = fmaf(a.y, b.w, acc[1][3]);
            acc[2][0] = fmaf(a.z, b.x, acc[2][0]); acc[2][1] = fmaf(a.z, b.y, acc[2][1]);
            acc[2][2] = fmaf(a.z, b.z, acc[2][2]); acc[2][3] = fmaf(a.z, b.w, acc[2][3]);
            acc[3][0] = fmaf(a.w, b.x, acc[3][0]); acc[3][1] = fmaf(a.w, b.y, acc[3][1]);
            acc[3][2] = fmaf(a.w, b.z, acc[3][2]); acc[3][3] = fmaf(a.w, b.w, acc[3][3]);
        }
    }

    if (n0 + tn < NPAD) {
        float4 bias = *(const float4*)(bc + n0 + tn);
#pragma unroll
        for (int i = 0; i < 4; i++) {
            float4 r;
            r.x = acc[i][0] + bias.x; r.y = acc[i][1] + bias.y;
            r.z = acc[i][2] + bias.z; r.w = acc[i][3] + bias.w;
            *(float4*)(P + (size_t)(m0 + tm + i) * NPAD + n0 + tn) = r;
        }
    }
}

// ---------------------------------------------------------------------------
// Kernel 3: persistent scan. One wave per batch element. No LDS, no barriers.
// Lane roles: 0..32 = LSTM neuron (holds wh rows {i,33+i,66+i,99+i} + c_i);
// 34..51 = layer0 output i-34; 52..63 = layer1 output i-52; 33..35 = layer2
// output i-33 (overlaid in wbig[72..131]). Broadcasts via v_readlane.
// ---------------------------------------------------------------------------
__global__ __launch_bounds__(64, 1) void scan_kernel(
    const float* __restrict__ P, const float* __restrict__ lstm_wh,
    const float* __restrict__ ff1w0, const float* __restrict__ ff2w0,
    const float* __restrict__ taw0, const float* __restrict__ tbw0,
    const float* __restrict__ ff1w1, const float* __restrict__ ff2w1,
    const float* __restrict__ taw1, const float* __restrict__ tbw1,
    const float* __restrict__ ff1b1, const float* __restrict__ ff2b1,
    const float* __restrict__ tab1, const float* __restrict__ tbb1,
    const float* __restrict__ ff1w2, const float* __restrict__ ff2w2,
    const float* __restrict__ taw2, const float* __restrict__ tbw2,
    const float* __restrict__ ff1b2, const float* __restrict__ ff2b2,
    const float* __restrict__ tab2, const float* __restrict__ tbb2,
    const float* __restrict__ mask1, const float* __restrict__ mask2,
    float* __restrict__ out)
{
    const int L = threadIdx.x;
    const int b = blockIdx.x;

    float wbig[132];
#pragma unroll
    for (int j = 0; j < 132; j++) wbig[j] = 0.f;
    float b1a = 0.f, b1b = 0.f, b1c = 0.f, b1d = 0.f;
    float b2a = 0.f, b2b = 0.f, b2c = 0.f, b2d = 0.f;

    if (L < 33) {
#pragma unroll
        for (int g = 0; g < 4; g++)
#pragma unroll
            for (int k = 0; k < 33; k++)
                wbig[g * 33 + k] = lstm_wh[(g * 33 + L) * 33 + k];
    } else if (L >= 52) {
        const int i1 = L - 52;
#pragma unroll
        for (int k = 0; k < 30; k++) {
            float m = mask1[i1 * 30 + k];
            wbig[k]      = ff1w1[i1 * 30 + k] * m;
            wbig[30 + k] = ff2w1[i1 * 30 + k] * m;
            wbig[60 + k] = taw1[i1 * 30 + k];
            wbig[90 + k] = tbw1[i1 * 30 + k];
        }
        b1a = ff1b1[i1]; b1b = ff2b1[i1]; b1c = tab1[i1]; b1d = tbb1[i1];
    } else {
        // lanes 33..51: layer0 weights (h-part cols 256..273; mask is all-ones there)
        int i0 = L - 34; i0 = (i0 < 0) ? 0 : i0;
#pragma unroll
        for (int k = 0; k < 18; k++) {
            wbig[k]      = ff1w0[i0 * 274 + 256 + k];
            wbig[18 + k] = ff2w0[i0 * 274 + 256 + k];
            wbig[36 + k] = taw0[i0 * 274 + 256 + k];
            wbig[54 + k] = tbw0[i0 * 274 + 256 + k];
        }
        if (L < 36) {
            const int i2 = L - 33;
#pragma unroll
            for (int k = 0; k < 15; k++) {
                float m = mask2[i2 * 15 + k];
                wbig[72 + k]  = ff1w2[i2 * 15 + k] * m;
                wbig[87 + k]  = ff2w2[i2 * 15 + k] * m;
                wbig[102 + k] = taw2[i2 * 15 + k];
                wbig[117 + k] = tbw2[i2 * 15 + k];
            }
            b2a = ff1b2[i2]; b2b = ff2b2[i2]; b2c = tab2[i2]; b2d = tbb2[i2];
        }
    }

    float hs[33];
#pragma unroll
    for (int k = 0; k < 33; k++) hs[k] = 0.f;
    float cc = 0.f;

    const float* pptr = P + (size_t)b * TSTEPS * NPAD + ((L < 52) ? 4 * L : 0);
    float4 pv = *(const float4*)pptr;
    float* outp = out + (size_t)b * TSTEPS * 3 + (L - 33);

#pragma unroll 1
    for (int t = 0; t < TSTEPS; t++) {
        // prefetch next step's row (one dwordx4/lane; hidden under compute)
        const float4 nv = *(const float4*)(pptr + ((t < TSTEPS - 1) ? NPAD : 0));
        pptr += NPAD;

        // ---- Phase G: LSTM (valid in lanes 0..32; others compute junk) ----
        float zx = pv.x, zy = pv.y, zz = pv.z, zw = pv.w;
#pragma unroll
        for (int k = 0; k < 33; k++) {
            zx = fmaf(wbig[k],      hs[k], zx);
            zy = fmaf(wbig[33 + k], hs[k], zy);
            zz = fmaf(wbig[66 + k], hs[k], zz);
            zw = fmaf(wbig[99 + k], hs[k], zw);
        }
        cc = cc * fsig(zz + 1.f) + ftanh(zx) * fsig(zy);
        const float hv = ftanh(cc) * fsig(zw);

        float hb[33];
#pragma unroll
        for (int k = 0; k < 33; k++) hb[k] = rl(hv, k);

        // ---- Phase L0 (valid in lanes 34..51) ----
        float a0 = pv.x, a1 = pv.y, a2 = pv.z, a3 = pv.w;
#pragma unroll
        for (int k = 0; k < 18; k++) {
            a0 = fmaf(wbig[k],      hb[k], a0);
            a1 = fmaf(wbig[18 + k], hb[k], a1);
            a2 = fmaf(wbig[36 + k], hb[k], a2);
            a3 = fmaf(wbig[54 + k], hb[k], a3);
        }
        const float g0 = cfc_comb(a0, a1, a2, a3);
#pragma unroll
        for (int k = 0; k < 18; k++) hs[k] = rl(g0, 34 + k);

        // ---- Phase L1 (valid in lanes 52..63), xc1 = [hs[0..17], hb[18..29]] ----
        float c0 = b1a, c1 = b1b, c2 = b1c, c3 = b1d;
#pragma unroll
        for (int k = 0; k < 30; k++) {
            const float xk = (k < 18) ? hs[k] : hb[k];
            c0 = fmaf(wbig[k],      xk, c0);
            c1 = fmaf(wbig[30 + k], xk, c1);
            c2 = fmaf(wbig[60 + k], xk, c2);
            c3 = fmaf(wbig[90 + k], xk, c3);
        }
        const float g1 = cfc_comb(c0, c1, c2, c3);
#pragma unroll
        for (int k = 0; k < 12; k++) hs[18 + k] = rl(g1, 52 + k);

        // ---- Phase L2 (valid in lanes 33..35), xc2 = [hs[18..29], hb[30..32]] ----
        float d0 = b2a, d1 = b2b, d2 = b2c, d3 = b2d;
#pragma unroll
        for (int k = 0; k < 15; k++) {
            const float xk = (k < 12) ? hs[18 + k] : hb[18 + k];
            d0 = fmaf(wbig[72 + k],  xk, d0);
            d1 = fmaf(wbig[87 + k],  xk, d1);
            d2 = fmaf(wbig[102 + k], xk, d2);
            d3 = fmaf(wbig[117 + k], xk, d3);
        }
        const float g2 = cfc_comb(d0, d1, d2, d3);
        if (L >= 33 && L < 36) outp[(size_t)t * 3] = g2;
#pragma unroll
        for (int k = 0; k < 3; k++) hs[30 + k] = rl(g2, 33 + k);

        pv = nv;
    }
}

// ---------------------------------------------------------------------------
extern "C" void kernel_launch(void* const* d_in, const int* in_sizes, int n_in,
                              void* d_out, int out_size, void* d_ws, size_t ws_size,
                              hipStream_t stream) {
    const float* x       = (const float*)d_in[0];
    const float* fc1_w   = (const float*)d_in[1];
    const float* fc1_b   = (const float*)d_in[2];
    const float* lstm_wi = (const float*)d_in[3];
    const float* lstm_bi = (const float*)d_in[4];
    const float* lstm_wh = (const float*)d_in[5];
    const float* ff1w0 = (const float*)d_in[6];
    const float* ff2w0 = (const float*)d_in[7];
    const float* taw0  = (const float*)d_in[8];
    const float* tbw0  = (const float*)d_in[9];
    const float* ff1b0 = (const float*)d_in[10];
    const float* ff2b0 = (const float*)d_in[11];
    const float* tab0  = (const float*)d_in[12];
    const float* tbb0  = (const float*)d_in[13];
    const float* ff1w1 = (const float*)d_in[14];
    const float* ff2w1 = (const float*)d_in[15];
    const float* taw1  = (const float*)d_in[16];
    const float* tbw1  = (const float*)d_in[17];
    const float* ff1b1 = (const float*)d_in[18];
    const float* ff2b1 = (const float*)d_in[19];
    const float* tab1  = (const float*)d_in[20];
    const float* tbb1  = (const float*)d_in[21];
    const float* ff1w2 = (const float*)d_in[22];
    const float* ff2w2 = (const float*)d_in[23];
    const float* taw2  = (const float*)d_in[24];
    const float* tbw2  = (const float*)d_in[25];
    const float* ff1b2 = (const float*)d_in[26];
    const float* ff2b2 = (const float*)d_in[27];
    const float* tab2  = (const float*)d_in[28];
    const float* tbb2  = (const float*)d_in[29];
    const float* mask0 = (const float*)d_in[30];
    const float* mask1 = (const float*)d_in[31];
    const float* mask2 = (const float*)d_in[32];

    float* Wc = (float*)d_ws;            // 512*256 floats
    float* bc = Wc + 512 * NW;           // 256 floats
    float* P  = bc + NW;                 // 32768*208 floats
    float* outp = (float*)d_out;

    fold_kernel<<<256, 256, 0, stream>>>(fc1_w, fc1_b, lstm_wi, lstm_bi,
                                         ff1w0, ff2w0, taw0, tbw0,
                                         ff1b0, ff2b0, tab0, tbb0, mask0, Wc, bc);
    gemm_kernel<<<dim3(BT / 64, 4), 256, 0, stream>>>(x, Wc, bc, P);
    scan_kernel<<<NBATCH, 64, 0, stream>>>(P, lstm_wh,
                                           ff1w0, ff2w0, taw0, tbw0,
                                           ff1w1, ff2w1, taw1, tbw1,
                                           ff1b1, ff2b1, tab1, tbb1,
                                           ff1w2, ff2w2, taw2, tbw2,
                                           ff1b2, ff2b2, tab2, tbb2,
                                           mask1, mask2, outp);
}

// Round 3
// 757.836 us; speedup vs baseline: 1.4284x; 1.2130x over previous
//
#include <hip/hip_runtime.h>
#include <hip/hip_bf16.h>

// Problem constants
#define BT 32768      // B*T = 64*512
#define TSTEPS 512
#define NBATCH 64
#define KDIM 512      // IN_DIM
#define NPAD 208      // P row stride
#define NW 256        // Wc padded cols

#define L2E 1.4426950408889634f
#define T2E 2.8853900817779268f

__device__ __forceinline__ float rl(float v, int lane) {
    return __int_as_float(__builtin_amdgcn_readlane(__float_as_int(v), lane));
}
__device__ __forceinline__ float bperm(int byteidx, float v) {
    return __int_as_float(__builtin_amdgcn_ds_bpermute(byteidx, __float_as_int(v)));
}
// unified activation: a * rcp(1 + exp2(s*x + sc)) + b
//   sigmoid(x):   s=-L2E, sc=0,    a=1, b=0
//   sigmoid(x+1): s=-L2E, sc=-L2E, a=1, b=0
//   tanh(x):      s=-T2E, sc=0,    a=2, b=-1   (saturates correctly at +/-inf)
__device__ __forceinline__ float actf(float x, float s, float sc, float a, float b) {
    float e = exp2f(fmaf(s, x, sc));
    return fmaf(a, __builtin_amdgcn_rcpf(1.f + e), b);
}

// P column layout (dot-major):
//   cols 0..127   = z dots 0..127            (dot d = gate*33 + neuron)
//   cols 128..191 = layer0 dots 0..63        (dot e = m*18 + i)
//   cols 192..195 = z dots 128..131
//   cols 196..203 = layer0 dots 64..71
//   cols 204..207 = pad (zeros)
__device__ __forceinline__ int permpos(int o) {
    if (o < 128) return o;          // z dots 0..127
    if (o < 132) return o + 64;     // z dots 128..131 -> 192..195
    if (o < 196) return o - 4;      // l0 dots 0..63   -> 128..191
    return o;                       // l0 dots 64..71 -> 196..203; pad stays
}

// ---------------------------------------------------------------------------
// Kernel 1: fold fc1 into the stacked scan-input projection (permuted cols).
// ---------------------------------------------------------------------------
__global__ __launch_bounds__(256) void fold_kernel(
    const float* __restrict__ fc1_w, const float* __restrict__ fc1_b,
    const float* __restrict__ lstm_wi, const float* __restrict__ lstm_bi,
    const float* __restrict__ ff1w0, const float* __restrict__ ff2w0,
    const float* __restrict__ taw0, const float* __restrict__ tbw0,
    const float* __restrict__ ff1b0, const float* __restrict__ ff2b0,
    const float* __restrict__ tab0, const float* __restrict__ tbb0,
    const float* __restrict__ mask0,
    float* __restrict__ Wc, float* __restrict__ bc)
{
    const int o = blockIdx.x;   // 0..255 logical output column
    const int t = threadIdx.x;  // 0..255 = latent index l
    const int p = permpos(o);
    __shared__ float wrow[256];
    __shared__ float red[256];

    float wl = 0.f, b0 = 0.f;
    if (o < 132)      { wl = lstm_wi[o * 256 + t];                         b0 = lstm_bi[o]; }
    else if (o < 150) { int i = o - 132; wl = ff1w0[i * 274 + t] * mask0[i * 274 + t]; b0 = ff1b0[i]; }
    else if (o < 168) { int i = o - 150; wl = ff2w0[i * 274 + t] * mask0[i * 274 + t]; b0 = ff2b0[i]; }
    else if (o < 186) { int i = o - 168; wl = taw0[i * 274 + t];           b0 = tab0[i]; }
    else if (o < 204) { int i = o - 186; wl = tbw0[i * 274 + t];           b0 = tbb0[i]; }
    wrow[t] = wl;
    __syncthreads();

    float acc0 = 0.f, acc1 = 0.f;
    for (int l = 0; l < 256; l++) {
        float w = wrow[l];
        acc0 = fmaf(fc1_w[l * 512 + t], w, acc0);
        acc1 = fmaf(fc1_w[l * 512 + t + 256], w, acc1);
    }
    Wc[(size_t)t * NW + p] = acc0;
    Wc[(size_t)(t + 256) * NW + p] = acc1;

    red[t] = fc1_b[t] * wl;
    __syncthreads();
    for (int s = 128; s > 0; s >>= 1) {
        if (t < s) red[t] += red[t + s];
        __syncthreads();
    }
    if (t == 0) bc[p] = red[0] + b0;
}

// ---------------------------------------------------------------------------
// Kernel 2: P[m][n] = sum_k X[m][k]*Wc[k][n] + bc[n], fp32 LDS-tiled GEMM.
// ---------------------------------------------------------------------------
__global__ __launch_bounds__(256) void gemm_kernel(
    const float* __restrict__ X, const float* __restrict__ Wc,
    const float* __restrict__ bc, float* __restrict__ P)
{
    __shared__ float As[16][68];
    __shared__ float Bs[16][64];
    const int tid = threadIdx.x;
    const int m0 = blockIdx.x * 64;
    const int n0 = blockIdx.y * 64;
    const int lr = tid >> 2;
    const int lc = (tid & 3) << 2;
    const int wr = tid >> 4;
    const int wc = (tid & 15) << 2;
    const int tm = (tid >> 4) << 2;
    const int tn = (tid & 15) << 2;

    float acc[4][4];
#pragma unroll
    for (int i = 0; i < 4; i++)
#pragma unroll
        for (int j = 0; j < 4; j++) acc[i][j] = 0.f;

    for (int k0 = 0; k0 < KDIM; k0 += 16) {
        float4 av = *(const float4*)(X + (size_t)(m0 + lr) * KDIM + k0 + lc);
        float4 bv = *(const float4*)(Wc + (size_t)(k0 + wr) * NW + n0 + wc);
        __syncthreads();
        As[lc + 0][lr] = av.x; As[lc + 1][lr] = av.y;
        As[lc + 2][lr] = av.z; As[lc + 3][lr] = av.w;
        *(float4*)&Bs[wr][wc] = bv;
        __syncthreads();
#pragma unroll
        for (int k = 0; k < 16; k++) {
            float4 a = *(const float4*)&As[k][tm];
            float4 b = *(const float4*)&Bs[k][tn];
            acc[0][0] = fmaf(a.x, b.x, acc[0][0]); acc[0][1] = fmaf(a.x, b.y, acc[0][1]);
            acc[0][2] = fmaf(a.x, b.z, acc[0][2]); acc[0][3] = fmaf(a.x, b.w, acc[0][3]);
            acc[1][0] = fmaf(a.y, b.x, acc[1][0]); acc[1][1] = fmaf(a.y, b.y, acc[1][1]);
            acc[1][2] = fmaf(a.y, b.z, acc[1][2]); acc[1][3] = fmaf(a.y, b.w, acc[1][3]);
            acc[2][0] = fmaf(a.z, b.x, acc[2][0]); acc[2][1] = fmaf(a.z, b.y, acc[2][1]);
            acc[2][2] = fmaf(a.z, b.z, acc[2][2]); acc[2][3] = fmaf(a.z, b.w, acc[2][3]);
            acc[3][0] = fmaf(a.w, b.x, acc[3][0]); acc[3][1] = fmaf(a.w, b.y, acc[3][1]);
            acc[3][2] = fmaf(a.w, b.z, acc[3][2]); acc[3][3] = fmaf(a.w, b.w, acc[3][3]);
        }
    }

    if (n0 + tn < NPAD) {
        float4 bias = *(const float4*)(bc + n0 + tn);
#pragma unroll
        for (int i = 0; i < 4; i++) {
            float4 r;
            r.x = acc[i][0] + bias.x; r.y = acc[i][1] + bias.y;
            r.z = acc[i][2] + bias.z; r.w = acc[i][3] + bias.w;
            *(float4*)(P + (size_t)(m0 + tm + i) * NPAD + n0 + tn) = r;
        }
    }
}

// ---------------------------------------------------------------------------
// Kernel 3: persistent scan, one wave per batch element.
// Dot-per-lane layout; all weight/state arrays register-resident (straight-
// line const-index code, no divergent array writes).
//   G:  loopA dots 0..63 (lane L), loopB dots 64..127, loopC dots 128..131
//       (lanes 0..3; others duplicate rows harmlessly).
//   L0: loopA dots 0..63, loopB dots 64..71 on lanes 4..11.
//   L1: dots 0..47 on lanes 0..47.   L2: dots 0..11 on lanes 0..11.
// Gathers via ds_bpermute of per-lane precomputed byte indices; h broadcasts
// via v_readlane.
// ---------------------------------------------------------------------------
__global__ __launch_bounds__(64, 1) void scan_kernel(
    const float* __restrict__ P, const float* __restrict__ lstm_wh,
    const float* __restrict__ ff1w0, const float* __restrict__ ff2w0,
    const float* __restrict__ taw0, const float* __restrict__ tbw0,
    const float* __restrict__ ff1w1, const float* __restrict__ ff2w1,
    const float* __restrict__ taw1, const float* __restrict__ tbw1,
    const float* __restrict__ ff1b1, const float* __restrict__ ff2b1,
    const float* __restrict__ tab1, const float* __restrict__ tbb1,
    const float* __restrict__ ff1w2, const float* __restrict__ ff2w2,
    const float* __restrict__ taw2, const float* __restrict__ tbw2,
    const float* __restrict__ ff1b2, const float* __restrict__ ff2b2,
    const float* __restrict__ tab2, const float* __restrict__ tbb2,
    const float* __restrict__ mask1, const float* __restrict__ mask2,
    float* __restrict__ out)
{
    const int L = threadIdx.x;
    const int b = blockIdx.x;

    // ---- G weights: rows L, 64+L, 128+(L&3) of stacked [132][33] lstm_wh ----
    float wA[33], wB[33], wC[33];
    {
        const int rC = 128 + (L & 3);
#pragma unroll
        for (int k = 0; k < 33; k++) {
            wA[k] = lstm_wh[L * 33 + k];
            wB[k] = lstm_wh[(64 + L) * 33 + k];
            wC[k] = lstm_wh[rC * 33 + k];
        }
    }
    // ---- L0 weights (h-part cols 256..273; recurrent mask block is ones) ----
    float w0A[18], w0B[18];
    {
        const int m = L / 18, i = L - m * 18;   // L<64 -> valid dot, m in 0..3
        const float* p0 = (m == 0) ? ff1w0 : (m == 1) ? ff2w0 : (m == 2) ? taw0 : tbw0;
        const int lb = (L < 4) ? 4 : ((L > 11) ? 11 : L);
        const int ib = lb + 6;                   // tbw0 rows 10..17 for dots 64..71
#pragma unroll
        for (int k = 0; k < 18; k++) {
            w0A[k] = p0[i * 274 + 256 + k];
            w0B[k] = tbw0[ib * 274 + 256 + k];
        }
    }
    // ---- L1 weights (full rows, len 30; ff rows masked) ----
    float w1[30], bias1;
    {
        const int d = (L < 48) ? L : 47;
        const int m = d / 12, i = d - m * 12;
        const float* p1 = (m == 0) ? ff1w1 : (m == 1) ? ff2w1 : (m == 2) ? taw1 : tbw1;
        const float* pb = (m == 0) ? ff1b1 : (m == 1) ? ff2b1 : (m == 2) ? tab1 : tbb1;
#pragma unroll
        for (int k = 0; k < 30; k++) {
            float mv = (m < 2) ? mask1[i * 30 + k] : 1.f;
            w1[k] = p1[i * 30 + k] * mv;
        }
        bias1 = (L < 48) ? pb[i] : 0.f;
    }
    // ---- L2 weights (full rows, len 15) ----
    float w2[15], bias2;
    {
        const int d = (L < 12) ? L : 11;
        const int m = d / 3, i = d - m * 3;
        const float* p2 = (m == 0) ? ff1w2 : (m == 1) ? ff2w2 : (m == 2) ? taw2 : tbw2;
        const float* pb = (m == 0) ? ff1b2 : (m == 1) ? ff2b2 : (m == 2) ? tab2 : tbb2;
#pragma unroll
        for (int k = 0; k < 15; k++) {
            float mv = (m < 2) ? mask2[i * 15 + k] : 1.f;
            w2[k] = p2[i * 15 + k] * mv;
        }
        bias2 = (L < 12) ? pb[i] : 0.f;
    }

    // ---- per-lane activation constants ----
    const float sA  = (L < 33) ? -T2E : -L2E;          // A: ia=tanh, ig=sig
    const float aA  = (L < 33) ? 2.f : 1.f;
    const float bA  = (L < 33) ? -1.f : 0.f;
    const float scB = (L >= 2 && L <= 34) ? -L2E : 0.f; // B: fg lanes get sig(x+1)
    const float s0  = (L < 36) ? -T2E : -L2E;
    const float a0c = (L < 36) ? 2.f : 1.f;
    const float b0c = (L < 36) ? -1.f : 0.f;
    const float s1  = (L < 24) ? -T2E : -L2E;
    const float a1c = (L < 24) ? 2.f : 1.f;
    const float b1c = (L < 24) ? -1.f : 0.f;
    const float s2  = (L < 6) ? -T2E : -L2E;
    const float a2c = (L < 6) ? 2.f : 1.f;
    const float b2c = (L < 6) ? -1.f : 0.f;

    // ---- per-lane bpermute byte indices (lane = (idx/4) & 63) ----
    const int xIgA = (4 * (33 + L)) & 255;
    const int xIgB = (4 * (L - 31)) & 255;
    const int xFg  = (4 * (2 + L)) & 255;
    const int xOgA = (4 * (35 + L)) & 255;
    const int xOgC = (4 * (L - 29)) & 255;
    const int x0s  = (4 * (L + 18)) & 255;   // L0: tbA / f2 gather
    const int x0tb = (4 * (L - 42)) & 255;   // L0: tb from loopB
    const int x0ti = (4 * (L + 36)) & 255;
    const int x1s  = (4 * (L + 12)) & 255;   // L1: tb / f2
    const int x1ti = (4 * (L + 24)) & 255;
    const int x2s  = (4 * (L + 3)) & 255;    // L2: tb / f2
    const int x2ti = (4 * (L + 6)) & 255;

    // ---- state ----
    float hs[33];
#pragma unroll
    for (int k = 0; k < 33; k++) hs[k] = 0.f;
    float cc = 0.f;

    const float* Pb = P + (size_t)b * TSTEPS * NPAD;
    float d1v = Pb[L], d2v = Pb[64 + L], d3v = Pb[128 + L], d4v = Pb[192 + L];
    float* outp = out + (size_t)b * TSTEPS * 3 + L;

#pragma unroll 1
    for (int t = 0; t < TSTEPS; t++) {
        const float* Pn = Pb + (size_t)((t < TSTEPS - 1) ? t + 1 : t) * NPAD;
        const float n1 = Pn[L], n2 = Pn[64 + L], n3 = Pn[128 + L], n4 = Pn[192 + L];

        // ---- Phase G: 132 gate dots in 3 shared loops ----
        float accA = d1v, accB = d2v, accC = d4v;
#pragma unroll
        for (int k = 0; k < 33; k++) {
            accA = fmaf(wA[k], hs[k], accA);
            accB = fmaf(wB[k], hs[k], accB);
            accC = fmaf(wC[k], hs[k], accC);
        }
        const float actA = actf(accA, sA, 0.f, aA, bA);
        const float actB = actf(accB, -L2E, scB, 1.f, 0.f);
        const float actC = actf(accC, -L2E, 0.f, 1.f, 0.f);
        const float gIgA = bperm(xIgA, actA);
        const float gIgB = bperm(xIgB, actB);
        const float gFg  = bperm(xFg, actB);
        const float gOgA = bperm(xOgA, actB);
        const float gOgC = bperm(xOgC, actC);
        const float IG = (L < 31) ? gIgA : gIgB;
        const float OG = (L < 29) ? gOgA : gOgC;
        cc = fmaf(cc, gFg, actA * IG);
        const float hv = actf(cc, -T2E, 0.f, 2.f, -1.f) * OG;

        float hb[33];
#pragma unroll
        for (int k = 0; k < 33; k++) hb[k] = rl(hv, k);

        // ---- Phase L0: 72 dots (len 18) in 2 shared loops ----
        float l0a = d3v, l0b = d4v;
#pragma unroll
        for (int k = 0; k < 18; k++) {
            l0a = fmaf(w0A[k], hb[k], l0a);
            l0b = fmaf(w0B[k], hb[k], l0b);
        }
        {
            const float tA = bperm(x0s, l0a);
            const float tB = bperm(x0tb, l0b);
            const float tb = (L < 46) ? tA : tB;          // ta-lanes 36..53
            const float xin = (L >= 36 && L < 54) ? l0a + tb : l0a;
            const float av = actf(xin, s0, 0.f, a0c, b0c);
            const float f2 = bperm(x0s, av);
            const float ti = bperm(x0ti, av);
            const float h0 = fmaf(ti, f2 - av, av);        // valid lanes 0..17
#pragma unroll
            for (int k = 0; k < 18; k++) hs[k] = rl(h0, k);
        }

        // ---- Phase L1: 48 dots (len 30), xc1 = [hs[0..17], hb[18..29]] ----
        float l1 = bias1;
#pragma unroll
        for (int k = 0; k < 30; k++) l1 = fmaf(w1[k], (k < 18) ? hs[k] : hb[k], l1);
        {
            const float tb = bperm(x1s, l1);
            const float xin = (L >= 24 && L < 36) ? l1 + tb : l1;
            const float av = actf(xin, s1, 0.f, a1c, b1c);
            const float f2 = bperm(x1s, av);
            const float ti = bperm(x1ti, av);
            const float h1 = fmaf(ti, f2 - av, av);        // valid lanes 0..11
#pragma unroll
            for (int k = 0; k < 12; k++) hs[18 + k] = rl(h1, k);
        }

        // ---- Phase L2: 12 dots (len 15), xc2 = [hs[18..29], hb[30..32]] ----
        float l2 = bias2;
#pragma unroll
        for (int k = 0; k < 15; k++) l2 = fmaf(w2[k], (k < 12) ? hs[18 + k] : hb[18 + k], l2);
        {
            const float tb = bperm(x2s, l2);
            const float xin = (L >= 6 && L < 9) ? l2 + tb : l2;
            const float av = actf(xin, s2, 0.f, a2c, b2c);
            const float f2 = bperm(x2s, av);
            const float ti = bperm(x2ti, av);
            const float h2 = fmaf(ti, f2 - av, av);        // valid lanes 0..2
            if (L < 3) outp[(size_t)t * 3] = h2;
            hs[30] = rl(h2, 0); hs[31] = rl(h2, 1); hs[32] = rl(h2, 2);
        }

        d1v = n1; d2v = n2; d3v = n3; d4v = n4;
    }
}

// ---------------------------------------------------------------------------
extern "C" void kernel_launch(void* const* d_in, const int* in_sizes, int n_in,
                              void* d_out, int out_size, void* d_ws, size_t ws_size,
                              hipStream_t stream) {
    const float* x       = (const float*)d_in[0];
    const float* fc1_w   = (const float*)d_in[1];
    const float* fc1_b   = (const float*)d_in[2];
    const float* lstm_wi = (const float*)d_in[3];
    const float* lstm_bi = (const float*)d_in[4];
    const float* lstm_wh = (const float*)d_in[5];
    const float* ff1w0 = (const float*)d_in[6];
    const float* ff2w0 = (const float*)d_in[7];
    const float* taw0  = (const float*)d_in[8];
    const float* tbw0  = (const float*)d_in[9];
    const float* ff1b0 = (const float*)d_in[10];
    const float* ff2b0 = (const float*)d_in[11];
    const float* tab0  = (const float*)d_in[12];
    const float* tbb0  = (const float*)d_in[13];
    const float* ff1w1 = (const float*)d_in[14];
    const float* ff2w1 = (const float*)d_in[15];
    const float* taw1  = (const float*)d_in[16];
    const float* tbw1  = (const float*)d_in[17];
    const float* ff1b1 = (const float*)d_in[18];
    const float* ff2b1 = (const float*)d_in[19];
    const float* tab1  = (const float*)d_in[20];
    const float* tbb1  = (const float*)d_in[21];
    const float* ff1w2 = (const float*)d_in[22];
    const float* ff2w2 = (const float*)d_in[23];
    const float* taw2  = (const float*)d_in[24];
    const float* tbw2  = (const float*)d_in[25];
    const float* ff1b2 = (const float*)d_in[26];
    const float* ff2b2 = (const float*)d_in[27];
    const float* tab2  = (const float*)d_in[28];
    const float* tbb2  = (const float*)d_in[29];
    const float* mask0 = (const float*)d_in[30];
    const float* mask1 = (const float*)d_in[31];
    const float* mask2 = (const float*)d_in[32];

    float* Wc = (float*)d_ws;            // 512*256 floats
    float* bc = Wc + 512 * NW;           // 256 floats
    float* P  = bc + NW;                 // 32768*208 floats (+256 slack after)
    float* outp = (float*)d_out;

    fold_kernel<<<256, 256, 0, stream>>>(fc1_w, fc1_b, lstm_wi, lstm_bi,
                                         ff1w0, ff2w0, taw0, tbw0,
                                         ff1b0, ff2b0, tab0, tbb0, mask0, Wc, bc);
    gemm_kernel<<<dim3(BT / 64, 4), 256, 0, stream>>>(x, Wc, bc, P);
    scan_kernel<<<NBATCH, 64, 0, stream>>>(P, lstm_wh,
                                           ff1w0, ff2w0, taw0, tbw0,
                                           ff1w1, ff2w1, taw1, tbw1,
                                           ff1b1, ff2b1, tab1, tbb1,
                                           ff1w2, ff2w2, taw2, tbw2,
                                           ff1b2, ff2b2, tab2, tbb2,
                                           mask1, mask2, outp);
}